// Round 1
// 628.675 us; speedup vs baseline: 2.4536x; 2.4536x over previous
//
#include <hip/hip_runtime.h>

#define DIM 128
#define NS  12   // SAMPLE

typedef _Float16 h2 __attribute__((ext_vector_type(2)));

struct __align__(16) SMem {
    h2    feat[NS][DIM / 2];   // f16 feature rows, 256 B each (broadcast-read)
    float agg1[NS][DIM];       // hop-1 level-1 aggregates for this node's 12 neighbors
    float part[NS][2];         // per-wave partial sums for the alpha scalars
    float nwsh[NS];            // neighbor weights for the current aggregate
    float fin[2][DIM];         // final-mix vectors (hidden, agg_hidden)
};

__device__ __forceinline__ h2 u2h(unsigned u) {
    union { unsigned u; h2 h; } x; x.u = u; return x.h;
}

// dot2: c += a.x*b.x + a.y*b.y with f32 accumulate (v_dot2_f32_f16)
__device__ __forceinline__ float dot2(h2 a, h2 b, float c) {
#if __has_builtin(__builtin_amdgcn_fdot2)
    return __builtin_amdgcn_fdot2(a, b, c, false);
#else
    return c + (float)a[0] * (float)b[0] + (float)a[1] * (float)b[1];
#endif
}

// ---------------------------------------------------------------------------
// One aggregate step, block-cooperative. Thread d owns channel d.
// Logit path (feat @ w1) runs with f16 inputs / f32 accumulation; the
// softmax and the PV weighted-sum stay full f32 (nbv registers are f32).
// Barrier contract identical to the f32 version: two collective barriers
// separate all cross-call LDS reuse.
// ---------------------------------------------------------------------------
__device__ __forceinline__ float aggregate_core(const int d, const float ih,
                                                const float* __restrict__ nbv,
                                                const h2* __restrict__ w1h,
                                                const float w1b, const float w2d,
                                                SMem& sm) {
    // stage feat row s as f16: feat[s][d] = ih * nbv[s]
    _Float16* fh = (_Float16*)&sm.feat[0][0];
#pragma unroll
    for (int s = 0; s < NS; ++s) fh[s * DIM + d] = (_Float16)(ih * nbv[s]);
    __syncthreads();

    // c[s] = lrelu(feat[s] @ w1, 0.2) * w2[d]   (per-thread column d)
    float c[NS];
#pragma unroll 1
    for (int s = 0; s < NS; ++s) {
        const uint4* row = (const uint4*)&sm.feat[s][0];
        float a0 = 0.f, a1 = 0.f, a2 = 0.f, a3 = 0.f;
#pragma unroll
        for (int q = 0; q < DIM / 8; ++q) {   // 16 x ds_read_b128, 64 x fdot2
            const uint4 r = row[q];
            a0 = dot2(u2h(r.x), w1h[q * 4 + 0], a0);
            a1 = dot2(u2h(r.y), w1h[q * 4 + 1], a1);
            a2 = dot2(u2h(r.z), w1h[q * 4 + 2], a2);
            a3 = dot2(u2h(r.w), w1h[q * 4 + 3], a3);
        }
        float acc = (a0 + a1) + (a2 + a3) + sm.nwsh[s] * w1b;
        acc = acc > 0.f ? acc : 0.2f * acc;    // leaky_relu(0.2)
        c[s] = acc * w2d;
    }

    // batched butterfly: 6 rounds x 12 independent adds (ILP) instead of
    // 12 serial 6-deep chains
#pragma unroll
    for (int off = 32; off > 0; off >>= 1) {
#pragma unroll
        for (int s = 0; s < NS; ++s) c[s] += __shfl_down(c[s], off, 64);
    }
    if ((d & 63) == 0) {
#pragma unroll
        for (int s = 0; s < NS; ++s) sm.part[s][d >> 6] = c[s];
    }
    __syncthreads();

    // softmax over the 12 scalars (redundant per thread, trivial cost)
    float a[NS], m = -1e30f;
#pragma unroll
    for (int s = 0; s < NS; ++s) {
        a[s] = sm.part[s][0] + sm.part[s][1];
        m = fmaxf(m, a[s]);
    }
    float sum = 0.f;
#pragma unroll
    for (int s = 0; s < NS; ++s) { a[s] = __expf(a[s] - m); sum += a[s]; }
    const float inv = 1.f / sum;
    float o = 0.f;
#pragma unroll
    for (int s = 0; s < NS; ++s) o = fmaf(a[s], nbv[s], o);  // PV in f32
    return o * inv;
}

// ---------------------------------------------------------------------------
// Fully fused: one block per output node n (3200 total). Zero workspace.
//   agg0   = aggregate(hidden[n],    nh1[n*12 .. +12),          nw0[n])
//   agg1_j = aggregate(nh1[n*12+j],  nh2[(n*12+j)*12 .. +12),   nw1[n*12+j])
//   agg2   = aggregate(agg0,         agg1[0..12),               nw0[n])
//   ah = s0*agg0 + s1*agg2 ; w = sigmoid(h@w3 + ah@w4) ; out = (1-w)h + w*ah
// __launch_bounds__(128,4): force VGPR<=128 -> 4 waves/SIMD (2x occupancy)
// ---------------------------------------------------------------------------
__global__ __launch_bounds__(128, 4) void fused_kernel(
    const float* __restrict__ hidden, const float* __restrict__ nh1,
    const float* __restrict__ nh2, const float* __restrict__ nw0,
    const float* __restrict__ nw1, const float* __restrict__ w1,
    const float* __restrict__ w2, const float* __restrict__ w3,
    const float* __restrict__ w4, const float* __restrict__ sv,
    float* __restrict__ out) {
    const int n = blockIdx.x;   // node 0..3199
    const int d = threadIdx.x;  // channel 0..127
    __shared__ SMem sm;

    // w1 column d as 64 packed f16 pairs (64 VGPRs) + f32 bias; reused by all
    // 14 aggregates. Half the register cost of the f32 column -> fits <=128.
    h2 w1h[DIM / 2];
#pragma unroll
    for (int k = 0; k < DIM / 2; ++k) {
        h2 t;
        t[0] = (_Float16)w1[(2 * k + 0) * DIM + d];
        t[1] = (_Float16)w1[(2 * k + 1) * DIM + d];
        w1h[k] = t;
    }
    const float w1b = w1[DIM * DIM + d];  // bias row (stays f32)
    const float w2d = w2[d];

    // ---- agg0 -----------------------------------------------------------
    const float ih0 = hidden[n * DIM + d];
    float nbv0[NS];  // nh1 rows n*12+j at channel d; doubles as agg1 items
#pragma unroll
    for (int s = 0; s < NS; ++s) nbv0[s] = nh1[(n * NS + s) * DIM + d];
    if (d < NS) sm.nwsh[d] = nw0[n * NS + d];
    const float agg0 = aggregate_core(d, ih0, nbv0, w1h, w1b, w2d, sm);

    // ---- agg1[j], j = 0..11 --------------------------------------------
#pragma unroll 1
    for (int j = 0; j < NS; ++j) {
        const size_t k = (size_t)(n * NS + j);
        float nbv[NS];
#pragma unroll
        for (int s = 0; s < NS; ++s) nbv[s] = nh2[(k * NS + s) * DIM + d];
        if (d < NS) sm.nwsh[d] = nw1[k * NS + d];
        sm.agg1[j][d] = aggregate_core(d, nbv0[j], nbv, w1h, w1b, w2d, sm);
    }
    __syncthreads();  // agg1 tile visible to all threads

    // ---- agg2 -----------------------------------------------------------
    float nbv2[NS];
#pragma unroll
    for (int s = 0; s < NS; ++s) nbv2[s] = sm.agg1[s][d];
    if (d < NS) sm.nwsh[d] = nw0[n * NS + d];
    const float agg2 = aggregate_core(d, agg0, nbv2, w1h, w1b, w2d, sm);

    // ---- final mix (full f32) ------------------------------------------
    const float ah = sv[0] * agg0 + sv[1] * agg2;
    sm.fin[0][d] = ih0;  // hidden vector
    sm.fin[1][d] = ah;   // aggregated vector
    __syncthreads();
    float t0 = 0.f, t1 = 0.f, t2 = 0.f, t3 = 0.f;
#pragma unroll
    for (int k = 0; k < DIM; k += 2) {
        t0 = fmaf(sm.fin[0][k],     w3[k * DIM + d],       t0);
        t1 = fmaf(sm.fin[1][k],     w4[k * DIM + d],       t1);
        t2 = fmaf(sm.fin[0][k + 1], w3[(k + 1) * DIM + d], t2);
        t3 = fmaf(sm.fin[1][k + 1], w4[(k + 1) * DIM + d], t3);
    }
    const float t = (t0 + t1) + (t2 + t3);
    const float w = 1.f / (1.f + __expf(-t));
    out[n * DIM + d] = (1.f - w) * ih0 + w * ah;
}

extern "C" void kernel_launch(void* const* d_in, const int* in_sizes, int n_in,
                              void* d_out, int out_size, void* d_ws, size_t ws_size,
                              hipStream_t stream) {
    const float* hidden = (const float*)d_in[0];  // [64,50,128]
    const float* nh1    = (const float*)d_in[1];  // [64,600,128]
    const float* nh2    = (const float*)d_in[2];  // [64,7200,128]
    const float* nw0    = (const float*)d_in[3];  // [64,50,12]
    const float* nw1    = (const float*)d_in[4];  // [64,600,12]
    const float* w1     = (const float*)d_in[5];  // [129,128]
    const float* w2     = (const float*)d_in[6];  // [128,1]
    const float* w3     = (const float*)d_in[7];  // [128,128]
    const float* w4     = (const float*)d_in[8];  // [128,128]
    const float* sv     = (const float*)d_in[9];  // [2,1]

    fused_kernel<<<3200, 128, 0, stream>>>(hidden, nh1, nh2, nw0, nw1, w1, w2,
                                           w3, w4, sv, (float*)d_out);
}

// Round 2
// 609.398 us; speedup vs baseline: 2.5312x; 1.0316x over previous
//
#include <hip/hip_runtime.h>

#define DIM 128
#define NS  12   // SAMPLE

typedef _Float16 h2 __attribute__((ext_vector_type(2)));

struct __align__(16) SMem {
    h2    feat[NS][DIM / 2];   // f16 feature rows, 256 B each (broadcast-read)
    float agg1[NS][DIM];       // hop-1 level-1 aggregates for this node's 12 neighbors
    float part[NS][2];         // per-wave partial sums for the alpha scalars
    float nwsh[NS];            // neighbor weights for the current aggregate
    float fin[2][DIM];         // final-mix vectors (hidden, agg_hidden)
};

__device__ __forceinline__ h2 u2h(unsigned u) {
    union { unsigned u; h2 h; } x; x.u = u; return x.h;
}

// dot2: c += a.x*b.x + a.y*b.y with f32 accumulate (v_dot2_f32_f16)
__device__ __forceinline__ float dot2(h2 a, h2 b, float c) {
#if __has_builtin(__builtin_amdgcn_fdot2)
    return __builtin_amdgcn_fdot2(a, b, c, false);
#else
    return c + (float)a[0] * (float)b[0] + (float)a[1] * (float)b[1];
#endif
}

// ---------------------------------------------------------------------------
// One aggregate step, block-cooperative. Thread d owns channel d.
// Logit path (feat @ w1) runs with f16 inputs / f32 accumulation; the
// softmax and the PV weighted-sum stay full f32 (nbv registers are f32).
// Barrier contract: two collective barriers separate all cross-call LDS reuse.
// ---------------------------------------------------------------------------
__device__ __forceinline__ float aggregate_core(const int d, const float ih,
                                                const float* __restrict__ nbv,
                                                const h2* __restrict__ w1h,
                                                const float w1b, const float w2d,
                                                SMem& sm) {
    // stage feat row s as f16: feat[s][d] = ih * nbv[s]
    _Float16* fh = (_Float16*)&sm.feat[0][0];
#pragma unroll
    for (int s = 0; s < NS; ++s) fh[s * DIM + d] = (_Float16)(ih * nbv[s]);
    __syncthreads();

    // c[s] = lrelu(feat[s] @ w1, 0.2) * w2[d]   (per-thread column d)
    float c[NS];
#pragma unroll 1
    for (int s = 0; s < NS; ++s) {
        const uint4* row = (const uint4*)&sm.feat[s][0];
        float a0 = 0.f, a1 = 0.f, a2 = 0.f, a3 = 0.f;
#pragma unroll
        for (int q = 0; q < DIM / 8; ++q) {   // 16 x ds_read_b128, 64 x fdot2
            const uint4 r = row[q];
            a0 = dot2(u2h(r.x), w1h[q * 4 + 0], a0);
            a1 = dot2(u2h(r.y), w1h[q * 4 + 1], a1);
            a2 = dot2(u2h(r.z), w1h[q * 4 + 2], a2);
            a3 = dot2(u2h(r.w), w1h[q * 4 + 3], a3);
        }
        float acc = (a0 + a1) + (a2 + a3) + sm.nwsh[s] * w1b;
        acc = acc > 0.f ? acc : 0.2f * acc;    // leaky_relu(0.2)
        c[s] = acc * w2d;
    }

    // batched butterfly: 6 rounds x 12 independent adds (ILP) instead of
    // 12 serial 6-deep chains
#pragma unroll
    for (int off = 32; off > 0; off >>= 1) {
#pragma unroll
        for (int s = 0; s < NS; ++s) c[s] += __shfl_down(c[s], off, 64);
    }
    if ((d & 63) == 0) {
#pragma unroll
        for (int s = 0; s < NS; ++s) sm.part[s][d >> 6] = c[s];
    }
    __syncthreads();

    // softmax over the 12 scalars (redundant per thread, trivial cost);
    // reuse c[] as the exp buffer to keep register pressure down
    float m = -1e30f;
#pragma unroll
    for (int s = 0; s < NS; ++s) {
        c[s] = sm.part[s][0] + sm.part[s][1];
        m = fmaxf(m, c[s]);
    }
    float sum = 0.f;
#pragma unroll
    for (int s = 0; s < NS; ++s) { c[s] = __expf(c[s] - m); sum += c[s]; }
    const float inv = 1.f / sum;
    float o = 0.f;
#pragma unroll
    for (int s = 0; s < NS; ++s) o = fmaf(c[s], nbv[s], o);  // PV in f32
    return o * inv;
}

// ---------------------------------------------------------------------------
// Fully fused: one block per output node n (3200 total). Zero workspace.
//   agg0   = aggregate(hidden[n],    nh1[n*12 .. +12),          nw0[n])
//   agg1_j = aggregate(nh1[n*12+j],  nh2[(n*12+j)*12 .. +12),   nw1[n*12+j])
//   agg2   = aggregate(agg0,         agg1[0..12),               nw0[n])
//   ah = s0*agg0 + s1*agg2 ; w = sigmoid(h@w3 + ah@w4) ; out = (1-w)h + w*ah
// __launch_bounds__(128,2): compiler treats arg2 as blocks/EU -> 4 waves/EU
// -> 128-VGPR cap. Natural demand ~115 -> no spills (R1's (128,4) forced a
// 64-reg cap and 118 MB of scratch traffic).
// ---------------------------------------------------------------------------
__global__ __launch_bounds__(128, 2) void fused_kernel(
    const float* __restrict__ hidden, const float* __restrict__ nh1,
    const float* __restrict__ nh2, const float* __restrict__ nw0,
    const float* __restrict__ nw1, const float* __restrict__ w1,
    const float* __restrict__ w2, const float* __restrict__ w3,
    const float* __restrict__ w4, const float* __restrict__ sv,
    float* __restrict__ out) {
    const int n = blockIdx.x;   // node 0..3199
    const int d = threadIdx.x;  // channel 0..127
    __shared__ SMem sm;

    // w1 column d as 64 packed f16 pairs (64 VGPRs) + f32 bias; reused by all
    // 14 aggregates.
    h2 w1h[DIM / 2];
#pragma unroll
    for (int k = 0; k < DIM / 2; ++k) {
        h2 t;
        t[0] = (_Float16)w1[(2 * k + 0) * DIM + d];
        t[1] = (_Float16)w1[(2 * k + 1) * DIM + d];
        w1h[k] = t;
    }
    const float w1b = w1[DIM * DIM + d];  // bias row (stays f32)
    const float w2d = w2[d];

    // ---- agg0 -----------------------------------------------------------
    const float ih0 = hidden[n * DIM + d];
    float nbv0[NS];  // nh1 rows n*12+j at channel d; reused as ih for agg1[j]
#pragma unroll
    for (int s = 0; s < NS; ++s) nbv0[s] = nh1[(n * NS + s) * DIM + d];
    if (d < NS) sm.nwsh[d] = nw0[n * NS + d];
    const float agg0 = aggregate_core(d, ih0, nbv0, w1h, w1b, w2d, sm);

    // ---- agg1[j], j = 0..11 --------------------------------------------
#pragma unroll 1
    for (int j = 0; j < NS; ++j) {
        const size_t k = (size_t)(n * NS + j);
        float nbv[NS];
#pragma unroll
        for (int s = 0; s < NS; ++s) nbv[s] = nh2[(k * NS + s) * DIM + d];
        if (d < NS) sm.nwsh[d] = nw1[k * NS + d];
        sm.agg1[j][d] = aggregate_core(d, nbv0[j], nbv, w1h, w1b, w2d, sm);
    }
    __syncthreads();  // agg1 tile visible to all threads

    // ---- agg2 (reuse nbv0 registers for the agg1 items) -----------------
    const float ih2 = agg0;
#pragma unroll
    for (int s = 0; s < NS; ++s) nbv0[s] = sm.agg1[s][d];
    if (d < NS) sm.nwsh[d] = nw0[n * NS + d];
    const float agg2 = aggregate_core(d, ih2, nbv0, w1h, w1b, w2d, sm);

    // ---- final mix (full f32) ------------------------------------------
    const float ah = sv[0] * agg0 + sv[1] * agg2;
    sm.fin[0][d] = ih0;  // hidden vector
    sm.fin[1][d] = ah;   // aggregated vector
    __syncthreads();
    float t0 = 0.f, t1 = 0.f, t2 = 0.f, t3 = 0.f;
#pragma unroll
    for (int k = 0; k < DIM; k += 2) {
        t0 = fmaf(sm.fin[0][k],     w3[k * DIM + d],       t0);
        t1 = fmaf(sm.fin[1][k],     w4[k * DIM + d],       t1);
        t2 = fmaf(sm.fin[0][k + 1], w3[(k + 1) * DIM + d], t2);
        t3 = fmaf(sm.fin[1][k + 1], w4[(k + 1) * DIM + d], t3);
    }
    const float t = (t0 + t1) + (t2 + t3);
    const float w = 1.f / (1.f + __expf(-t));
    out[n * DIM + d] = (1.f - w) * ih0 + w * ah;
}

extern "C" void kernel_launch(void* const* d_in, const int* in_sizes, int n_in,
                              void* d_out, int out_size, void* d_ws, size_t ws_size,
                              hipStream_t stream) {
    const float* hidden = (const float*)d_in[0];  // [64,50,128]
    const float* nh1    = (const float*)d_in[1];  // [64,600,128]
    const float* nh2    = (const float*)d_in[2];  // [64,7200,128]
    const float* nw0    = (const float*)d_in[3];  // [64,50,12]
    const float* nw1    = (const float*)d_in[4];  // [64,600,12]
    const float* w1     = (const float*)d_in[5];  // [129,128]
    const float* w2     = (const float*)d_in[6];  // [128,1]
    const float* w3     = (const float*)d_in[7];  // [128,128]
    const float* w4     = (const float*)d_in[8];  // [128,128]
    const float* sv     = (const float*)d_in[9];  // [2,1]

    fused_kernel<<<3200, 128, 0, stream>>>(hidden, nh1, nh2, nw0, nw1, w1, w2,
                                           w3, w4, sv, (float*)d_out);
}

// Round 4
// 387.874 us; speedup vs baseline: 3.9769x; 1.5711x over previous
//
#include <hip/hip_runtime.h>

#define DIM 128
#define NS  12   // SAMPLE

typedef _Float16 f16x8 __attribute__((ext_vector_type(8)));
typedef float    f32x4 __attribute__((ext_vector_type(4)));

// v_mfma_f32_16x16x32_f16 (gfx950-native, guide §3): D[i][j] += sum_k A[i][k]*B[k][j]
// A: lane l holds A[l&15][8*(l>>4)+j], j=0..7   (k-contiguous, m97-consistent)
// B: lane l holds B[8*(l>>4)+j][l&15]
// C/D: lane l holds C[4*(l>>4)+r][l&15], r=0..3 (m89-verified, dtype-independent)
#define MFMA32(a, b, c) __builtin_amdgcn_mfma_f32_16x16x32_f16((a), (b), (c), 0, 0, 0)

struct __align__(16) SMem {
    // feat row m (m=0..15) at halves m*128; half index = m*128 + (k ^ (m<<3))
    // XOR swizzle (bits>=3 only) keeps b128 reads 8-half-contiguous while
    // spreading the 16 mm rows across bank groups (b128 8-phase floor).
    _Float16 feat[16 * DIM];
    float agg1[NS][DIM];   // hop-1 level-1 aggregates
    float part[2][16];     // per-wave alpha-logit partials (rows 12..15 unused)
    float nwsh[16];        // neighbor weights, padded with zeros
    float fin[2][DIM];     // final-mix vectors
};

template <int CTRL>
__device__ __forceinline__ float dpp_add(float v) {
    // VALU-pipe cross-lane add (no DS traffic)
    int t = __builtin_amdgcn_update_dpp(0, __float_as_int(v), CTRL, 0xf, 0xf, false);
    return v + __int_as_float(t);
}

// ---------------------------------------------------------------------------
// One aggregate step. Logits via MFMA (f16 inputs, f32 accum); softmax and PV
// stay f32. Thread d owns output channel d for staging and PV; MFMA fragments
// use (wid, g=lane>>4, mm=lane&15).
// Barrier contract: two collective barriers (sync1 after stage, sync2 after
// part-write) separate all cross-call LDS reuse.
// ---------------------------------------------------------------------------
__device__ __forceinline__ float agg_mfma(const int d, const int wid, const int g,
                                          const int mm, const float ih,
                                          const float* __restrict__ nbv,
                                          const f16x8 (&bf)[4][4],
                                          const f32x4 w1bf, const f32x4 w2f,
                                          SMem& sm) {
    // ---- stage feat rows 0..11 as f16, swizzled ----
#pragma unroll
    for (int s = 0; s < NS; ++s)
        sm.feat[s * DIM + (d ^ (s << 3))] = (_Float16)(ih * nbv[s]);
    __syncthreads();

    // ---- logits[s][dcol] via MFMA: c{nt}[r] = logits[4g+r][wid*64+nt*16+mm] ----
    const f32x4 zero = {0.f, 0.f, 0.f, 0.f};
    f32x4 c0 = zero, c1 = zero, c2 = zero, c3 = zero;
    const int abase = mm * DIM;
    const int mx = mm << 3;
#pragma unroll
    for (int kk = 0; kk < 4; ++kk) {   // K = 4 x 32
        const f16x8 a =
            *(const f16x8*)&sm.feat[abase + (((kk << 5) + (g << 3)) ^ mx)];
        c0 = MFMA32(a, bf[kk][0], c0);
        c1 = MFMA32(a, bf[kk][1], c1);
        c2 = MFMA32(a, bf[kk][2], c2);
        c3 = MFMA32(a, bf[kk][3], c3);
    }

    // ---- bias + leaky_relu(0.2) + w2 weighting ----
    const f32x4 nw4 = *(const f32x4*)&sm.nwsh[g * 4];
    float val[4];
#pragma unroll
    for (int r = 0; r < 4; ++r) {
        float t0 = c0[r] + nw4[r] * w1bf[0];
        float t1 = c1[r] + nw4[r] * w1bf[1];
        float t2 = c2[r] + nw4[r] * w1bf[2];
        float t3 = c3[r] + nw4[r] * w1bf[3];
        t0 = t0 > 0.f ? t0 : 0.2f * t0;
        t1 = t1 > 0.f ? t1 : 0.2f * t1;
        t2 = t2 > 0.f ? t2 : 0.2f * t2;
        t3 = t3 > 0.f ? t3 : 0.2f * t3;
        val[r] = fmaf(t0, w2f[0], fmaf(t1, w2f[1], fmaf(t2, w2f[2], t3 * w2f[3])));
    }

    // ---- reduce over the 16 cols held by this lane group: DPP butterfly ----
#pragma unroll
    for (int r = 0; r < 4; ++r) {
        val[r] = dpp_add<0xB1>(val[r]);    // quad_perm [1,0,3,2]
        val[r] = dpp_add<0x4E>(val[r]);    // quad_perm [2,3,0,1]
        val[r] = dpp_add<0x124>(val[r]);   // row_ror:4
        val[r] = dpp_add<0x128>(val[r]);   // row_ror:8
    }
    if (mm == 0) {
        const f32x4 v = {val[0], val[1], val[2], val[3]};
        *(f32x4*)&sm.part[wid][g * 4] = v;   // logits rows 4g..4g+3, this wave
    }
    __syncthreads();

    // ---- softmax over 12 logits (redundant per thread) + PV in f32 ----
    const f32x4 pa0 = *(const f32x4*)&sm.part[0][0];
    const f32x4 pa1 = *(const f32x4*)&sm.part[0][4];
    const f32x4 pa2 = *(const f32x4*)&sm.part[0][8];
    const f32x4 pb0 = *(const f32x4*)&sm.part[1][0];
    const f32x4 pb1 = *(const f32x4*)&sm.part[1][4];
    const f32x4 pb2 = *(const f32x4*)&sm.part[1][8];
    const f32x4 q0 = pa0 + pb0, q1 = pa1 + pb1, q2 = pa2 + pb2;
    float cc[NS] = {q0[0], q0[1], q0[2], q0[3], q1[0], q1[1], q1[2], q1[3],
                    q2[0], q2[1], q2[2], q2[3]};
    float m = -1e30f;
#pragma unroll
    for (int s = 0; s < NS; ++s) m = fmaxf(m, cc[s]);
    float sum = 0.f;
#pragma unroll
    for (int s = 0; s < NS; ++s) { cc[s] = __expf(cc[s] - m); sum += cc[s]; }
    const float inv = 1.f / sum;
    float o0 = 0.f, o1 = 0.f, o2 = 0.f, o3 = 0.f;
#pragma unroll
    for (int s = 0; s < NS; s += 4) {
        o0 = fmaf(cc[s + 0], nbv[s + 0], o0);
        o1 = fmaf(cc[s + 1], nbv[s + 1], o1);
        o2 = fmaf(cc[s + 2], nbv[s + 2], o2);
        o3 = fmaf(cc[s + 3], nbv[s + 3], o3);
    }
    return ((o0 + o1) + (o2 + o3)) * inv;
}

// ---------------------------------------------------------------------------
// One block per output node n (3200 total), 128 threads = 2 waves.
// Wave wid owns output cols wid*64..wid*64+63 of the logit matmul; w1 lives
// in registers as 16 B-fragments per wave (64 VGPRs, reused by 14 aggregates).
// ---------------------------------------------------------------------------
__global__ __launch_bounds__(128) void fused_kernel(
    const float* __restrict__ hidden, const float* __restrict__ nh1,
    const float* __restrict__ nh2, const float* __restrict__ nw0,
    const float* __restrict__ nw1, const float* __restrict__ w1,
    const float* __restrict__ w2, const float* __restrict__ w3,
    const float* __restrict__ w4, const float* __restrict__ sv,
    float* __restrict__ out) {
    const int n = blockIdx.x;   // node 0..3199
    const int d = threadIdx.x;  // channel 0..127
    const int wid = d >> 6, l = d & 63, g = l >> 4, mm = l & 15;
    __shared__ SMem sm;

    // zero the pad rows (A rows 12..15 must be 0; nwsh pad likewise) — once;
    // first agg's sync1 makes them visible. Rows 12..15 are never re-staged.
#pragma unroll
    for (int m = NS; m < 16; ++m)
        sm.feat[m * DIM + (d ^ (m << 3))] = (_Float16)0.f;
    if (d >= NS && d < 16) sm.nwsh[d] = 0.f;

    // ---- w1 B-fragments (f16) + bias/w2 fragments (f32), per wave ----
    f16x8 bf[4][4];
    const int colb = wid * 64 + mm;
#pragma unroll
    for (int kk = 0; kk < 4; ++kk) {
#pragma unroll
        for (int nt = 0; nt < 4; ++nt) {
            f16x8 t;
#pragma unroll
            for (int j = 0; j < 8; ++j)
                t[j] = (_Float16)w1[(kk * 32 + g * 8 + j) * DIM + colb + nt * 16];
            bf[kk][nt] = t;
        }
    }
    f32x4 w1bf, w2f;
#pragma unroll
    for (int nt = 0; nt < 4; ++nt) {
        w1bf[nt] = w1[DIM * DIM + colb + nt * 16];  // bias row (f32)
        w2f[nt]  = w2[colb + nt * 16];
    }

    // ---- agg0 -----------------------------------------------------------
    const float ih0 = hidden[n * DIM + d];
    float nbv0[NS];  // nh1 rows at channel d; doubles as ih for agg1[j]
#pragma unroll
    for (int s = 0; s < NS; ++s) nbv0[s] = nh1[(n * NS + s) * DIM + d];
    if (d < NS) sm.nwsh[d] = nw0[n * NS + d];
    const float agg0 = agg_mfma(d, wid, g, mm, ih0, nbv0, bf, w1bf, w2f, sm);

    // ---- agg1[j], j = 0..11 --------------------------------------------
#pragma unroll 1
    for (int j = 0; j < NS; ++j) {
        const size_t k = (size_t)(n * NS + j);
        float nbv[NS];
#pragma unroll
        for (int s = 0; s < NS; ++s) nbv[s] = nh2[(k * NS + s) * DIM + d];
        if (d < NS) sm.nwsh[d] = nw1[k * NS + d];
        sm.agg1[j][d] = agg_mfma(d, wid, g, mm, nbv0[j], nbv, bf, w1bf, w2f, sm);
    }
    __syncthreads();  // agg1 tile visible to all threads

    // ---- agg2 (reuse nbv0 registers for the agg1 items) -----------------
    const float ih2 = agg0;
#pragma unroll
    for (int s = 0; s < NS; ++s) nbv0[s] = sm.agg1[s][d];
    if (d < NS) sm.nwsh[d] = nw0[n * NS + d];
    const float agg2 = agg_mfma(d, wid, g, mm, ih2, nbv0, bf, w1bf, w2f, sm);

    // ---- final mix (full f32, vectorized LDS reads) ---------------------
    const float ah = sv[0] * agg0 + sv[1] * agg2;
    sm.fin[0][d] = ih0;
    sm.fin[1][d] = ah;
    __syncthreads();
    float t0 = 0.f, t1 = 0.f, t2 = 0.f, t3 = 0.f;
#pragma unroll
    for (int k = 0; k < DIM; k += 4) {
        const f32x4 h4 = *(const f32x4*)&sm.fin[0][k];
        const f32x4 a4 = *(const f32x4*)&sm.fin[1][k];
        t0 = fmaf(h4[0], w3[(k + 0) * DIM + d], t0);
        t1 = fmaf(h4[1], w3[(k + 1) * DIM + d], t1);
        t2 = fmaf(h4[2], w3[(k + 2) * DIM + d], t2);
        t3 = fmaf(h4[3], w3[(k + 3) * DIM + d], t3);
        t0 = fmaf(a4[0], w4[(k + 0) * DIM + d], t0);
        t1 = fmaf(a4[1], w4[(k + 1) * DIM + d], t1);
        t2 = fmaf(a4[2], w4[(k + 2) * DIM + d], t2);
        t3 = fmaf(a4[3], w4[(k + 3) * DIM + d], t3);
    }
    const float t = (t0 + t1) + (t2 + t3);
    const float w = 1.f / (1.f + __expf(-t));
    out[n * DIM + d] = (1.f - w) * ih0 + w * ah;
}

extern "C" void kernel_launch(void* const* d_in, const int* in_sizes, int n_in,
                              void* d_out, int out_size, void* d_ws, size_t ws_size,
                              hipStream_t stream) {
    const float* hidden = (const float*)d_in[0];  // [64,50,128]
    const float* nh1    = (const float*)d_in[1];  // [64,600,128]
    const float* nh2    = (const float*)d_in[2];  // [64,7200,128]
    const float* nw0    = (const float*)d_in[3];  // [64,50,12]
    const float* nw1    = (const float*)d_in[4];  // [64,600,12]
    const float* w1     = (const float*)d_in[5];  // [129,128]
    const float* w2     = (const float*)d_in[6];  // [128,1]
    const float* w3     = (const float*)d_in[7];  // [128,128]
    const float* w4     = (const float*)d_in[8];  // [128,128]
    const float* sv     = (const float*)d_in[9];  // [2,1]

    fused_kernel<<<3200, 128, 0, stream>>>(hidden, nh1, nh2, nw0, nw1, w1, w2,
                                           w3, w4, sv, (float*)d_out);
}